// Round 1
// baseline (1405.465 us; speedup 1.0000x reference)
//
#include <hip/hip_runtime.h>
#include <hip/hip_bf16.h>
#include <math.h>

// Shapes
#define BB 2
#define DIM 384
#define HID 384
#define HH 256
#define WW 256
#define HW 65536          // 256*256
#define NPIX (BB*HW)

// ---------------------------------------------------------------------------
// Kernel A: precompute per-channel 8x8 circular-correlation taps from fft_filter
// K_c[a][b] = (1/64) sum_{u'=0..7} sum_{v'=0..4} w[v'] F[c][u'][v'] cos(2pi(a u' + b v')/8)
// ---------------------------------------------------------------------------
__global__ void k_precompute(const float* __restrict__ F, float* __restrict__ K) {
    int c = blockIdx.x;      // 0..383
    int t = threadIdx.x;     // 0..63
    int a = t >> 3, b = t & 7;
    const float ctab[8] = {1.f, 0.70710678118654752f, 0.f, -0.70710678118654752f,
                           -1.f, -0.70710678118654752f, 0.f, 0.70710678118654752f};
    const float* Fc = F + c * 40;
    float acc = 0.f;
#pragma unroll
    for (int up = 0; up < 8; ++up) {
#pragma unroll
        for (int vp = 0; vp < 5; ++vp) {
            float wv = (vp == 0 || vp == 4) ? 1.f : 2.f;
            int k = (a * up + b * vp) & 7;
            acc += wv * Fc[up * 5 + vp] * ctab[k];
        }
    }
    K[c * 64 + t] = acc * (1.f / 64.f);
}

// ---------------------------------------------------------------------------
// Tiled fp32 GEMM: C[z][m][n] = sum_k A[m][k] * B[z][k][n]
// A: M x K row-major (shared over z). B: z-strided K x N. C: z-strided M x N.
// 64x64 tile, K-tile 16, 256 threads, 4x4 accum per thread.
// ---------------------------------------------------------------------------
__global__ __launch_bounds__(256) void k_gemm(const float* __restrict__ A,
                                              const float* __restrict__ Bg,
                                              float* __restrict__ Cg,
                                              int M, int N, int Kd) {
    __shared__ float As[16][64];
    __shared__ float Bs[16][64];
    const float* B = Bg + (size_t)blockIdx.z * Kd * N;
    float* C = Cg + (size_t)blockIdx.z * M * N;
    int n0 = blockIdx.x * 64;
    int m0 = blockIdx.y * 64;
    int tid = threadIdx.x;
    int tx = tid & 15, ty = tid >> 4;
    int lm = tid & 63;   // 0..63
    int lk4 = tid >> 6;  // 0..3
    float acc[4][4] = {};
    for (int k0 = 0; k0 < Kd; k0 += 16) {
        float4 av = *(const float4*)(A + (size_t)(m0 + lm) * Kd + k0 + lk4 * 4);
        As[lk4 * 4 + 0][lm] = av.x;
        As[lk4 * 4 + 1][lm] = av.y;
        As[lk4 * 4 + 2][lm] = av.z;
        As[lk4 * 4 + 3][lm] = av.w;
#pragma unroll
        for (int j = 0; j < 4; ++j) {
            Bs[lk4 + j * 4][lm] = B[(size_t)(k0 + lk4 + j * 4) * N + n0 + lm];
        }
        __syncthreads();
#pragma unroll
        for (int kk = 0; kk < 16; ++kk) {
            float a[4], b[4];
#pragma unroll
            for (int i = 0; i < 4; ++i) a[i] = As[kk][ty * 4 + i];
#pragma unroll
            for (int j = 0; j < 4; ++j) b[j] = Bs[kk][tx * 4 + j];
#pragma unroll
            for (int i = 0; i < 4; ++i)
#pragma unroll
                for (int j = 0; j < 4; ++j) acc[i][j] += a[i] * b[j];
        }
        __syncthreads();
    }
#pragma unroll
    for (int i = 0; i < 4; ++i) {
        float4 v = make_float4(acc[i][0], acc[i][1], acc[i][2], acc[i][3]);
        *(float4*)(C + (size_t)(m0 + ty * 4 + i) * N + n0 + tx * 4) = v;
    }
}

// ---------------------------------------------------------------------------
// Kernel C: in-place per-patch 8x8 circular cross-correlation with K_c.
// Block = 256 threads handles 4 horizontally-consecutive patches (same b,c,ph).
// ---------------------------------------------------------------------------
__global__ __launch_bounds__(256) void k_circ(float* __restrict__ T, const float* __restrict__ K) {
    int id = blockIdx.x;
    int pwg = id & 7;  id >>= 3;   // 8 groups of 4 patches across width
    int ph  = id & 31; id >>= 5;   // 32 patch rows
    int c = id % 384;
    int b = id / 384;
    int tid = threadIdx.x;
    __shared__ float P[8][32];     // [patch row][4 patches * 8 cols]
    __shared__ float Kc[64];
    size_t base = ((size_t)(b * 384 + c) << 16) + ((size_t)(ph * 8) << 8) + (size_t)pwg * 32;
    int r = tid >> 5, cc = tid & 31;
    P[r][cc] = T[base + (size_t)r * 256 + cc];
    if (tid < 64) Kc[tid] = K[c * 64 + tid];
    __syncthreads();
    int patch = cc >> 3, v = cc & 7, u = r;
    float acc = 0.f;
#pragma unroll
    for (int a = 0; a < 8; ++a) {       // row shift
#pragma unroll
        for (int bs = 0; bs < 8; ++bs) { // col shift
            int p = (u + a) & 7;
            int q = (v + bs) & 7;
            acc += Kc[a * 8 + bs] * P[p][patch * 8 + q];
        }
    }
    T[base + (size_t)u * 256 + cc] = acc;
}

// ---------------------------------------------------------------------------
// Kernel D: depthwise 3x3 conv (SAME, zero pad) on channels c and c+192,
// then g = gelu_exact(z1) * z2. Tile 32x32, LDS-staged 34x34 halo.
// ---------------------------------------------------------------------------
__global__ __launch_bounds__(256) void k_dwgate(const float* __restrict__ Y,
                                                const float* __restrict__ Wdw,
                                                float* __restrict__ G) {
    int bz = blockIdx.z;
    int b = bz / 192;
    int c = bz % 192;
    int h0 = blockIdx.y * 32, w0 = blockIdx.x * 32;
    __shared__ float s1[34 * 34];
    __shared__ float s2[34 * 34];
    const float* Y1 = Y + ((size_t)(b * 384 + c) << 16);
    const float* Y2 = Y + ((size_t)(b * 384 + c + 192) << 16);
    int tid = threadIdx.x;
    for (int i = tid; i < 34 * 34; i += 256) {
        int r = i / 34, cl = i % 34;
        int gh = h0 + r - 1, gw = w0 + cl - 1;
        bool ok = (gh >= 0 && gh < 256 && gw >= 0 && gw < 256);
        float v1 = 0.f, v2 = 0.f;
        if (ok) {
            size_t off = (size_t)gh * 256 + gw;
            v1 = Y1[off];
            v2 = Y2[off];
        }
        s1[i] = v1;
        s2[i] = v2;
    }
    float wa[9], wb[9];
#pragma unroll
    for (int j = 0; j < 9; ++j) {
        wa[j] = Wdw[c * 9 + j];
        wb[j] = Wdw[(c + 192) * 9 + j];
    }
    __syncthreads();
    float* Gc = G + ((size_t)(b * 192 + c) << 16);
#pragma unroll
    for (int kq = 0; kq < 4; ++kq) {
        int idx = tid + kq * 256;
        int r = idx >> 5, cl = idx & 31;
        float z1 = 0.f, z2 = 0.f;
#pragma unroll
        for (int i = 0; i < 3; ++i)
#pragma unroll
            for (int j = 0; j < 3; ++j) {
                float p1 = s1[(r + i) * 34 + cl + j];
                float p2 = s2[(r + i) * 34 + cl + j];
                z1 += p1 * wa[i * 3 + j];
                z2 += p2 * wb[i * 3 + j];
            }
        float ge = 0.5f * z1 * (1.f + erff(z1 * 0.70710678118654752f));
        Gc[(size_t)(h0 + r) * 256 + w0 + cl] = ge * z2;
    }
}

// ---------------------------------------------------------------------------
extern "C" void kernel_launch(void* const* d_in, const int* in_sizes, int n_in,
                              void* d_out, int out_size, void* d_ws, size_t ws_size,
                              hipStream_t stream) {
    const float* x     = (const float*)d_in[0];  // (2,384,256,256)
    const float* ff    = (const float*)d_in[1];  // (384,8,5)
    const float* w_in  = (const float*)d_in[2];  // (384,384)
    const float* w_dw  = (const float*)d_in[3];  // (384,1,3,3)
    const float* w_out = (const float*)d_in[4];  // (384,192)
    float* out = (float*)d_out;                  // (2,384,256,256)

    float* Kbuf = (float*)d_ws;                                     // 384*64 floats = 96 KiB
    float* T    = (float*)((char*)d_ws + 98304);                    // 2*384*65536 f32 = 192 MiB
    float* G    = (float*)((char*)d_ws + 98304 + (size_t)201326592);// 2*192*65536 f32 = 96 MiB

    // A: per-channel circular-conv taps
    k_precompute<<<384, 64, 0, stream>>>(ff, Kbuf);

    // B: t = w_in @ x   (M=384, N=65536 per batch, K=384)
    {
        dim3 grid(HW / 64, HID / 64, BB);
        k_gemm<<<grid, 256, 0, stream>>>(w_in, x, T, HID, HW, DIM);
    }

    // C: per-patch circular conv, in place on T
    k_circ<<<BB * 384 * 32 * 8, 256, 0, stream>>>(T, Kbuf);

    // D: depthwise 3x3 + gelu-gate -> G (192 channels per batch)
    {
        dim3 grid(WW / 32, HH / 32, BB * 192);
        k_dwgate<<<grid, 256, 0, stream>>>(T, w_dw, G);
    }

    // E: out = w_out @ g  (M=384, N=65536 per batch, K=192)
    {
        dim3 grid(HW / 64, HID / 64, BB);
        k_gemm<<<grid, 256, 0, stream>>>(w_out, G, out, DIM, HW, HID / 2);
    }
}

// Round 2
// 699.476 us; speedup vs baseline: 2.0093x; 2.0093x over previous
//
#include <hip/hip_runtime.h>
#include <hip/hip_bf16.h>
#include <math.h>

#define BB 2
#define DIM 384
#define HID 384
#define HW 65536

typedef short s16x8 __attribute__((ext_vector_type(8)));
typedef __bf16 bf16x8 __attribute__((ext_vector_type(8)));
typedef float f32x4 __attribute__((ext_vector_type(4)));

__device__ inline short f2b(float f) {
    __hip_bfloat16 h = __float2bfloat16(f);
    return __builtin_bit_cast(short, h);
}

__device__ inline void gl_lds16(const short* g, short* l) {
    __builtin_amdgcn_global_load_lds(
        (const __attribute__((address_space(1))) unsigned int*)g,
        (__attribute__((address_space(3))) unsigned int*)l, 16, 0, 0);
}

// ---------------------------------------------------------------------------
// A: per-channel 8x8 circular-correlation taps from fft_filter
// ---------------------------------------------------------------------------
__global__ void k_precompute(const float* __restrict__ F, float* __restrict__ K) {
    int c = blockIdx.x;
    int t = threadIdx.x;
    int a = t >> 3, b = t & 7;
    const float ctab[8] = {1.f, 0.70710678118654752f, 0.f, -0.70710678118654752f,
                           -1.f, -0.70710678118654752f, 0.f, 0.70710678118654752f};
    const float* Fc = F + c * 40;
    float acc = 0.f;
#pragma unroll
    for (int up = 0; up < 8; ++up) {
#pragma unroll
        for (int vp = 0; vp < 5; ++vp) {
            float wv = (vp == 0 || vp == 4) ? 1.f : 2.f;
            int k = (a * up + b * vp) & 7;
            acc += wv * Fc[up * 5 + vp] * ctab[k];
        }
    }
    K[c * 64 + t] = acc * (1.f / 64.f);
}

// ---------------------------------------------------------------------------
// elementwise fp32 -> bf16 (weights)
// ---------------------------------------------------------------------------
__global__ void k_cvtw(const float* __restrict__ in, short* __restrict__ out, int n) {
    int i = blockIdx.x * 256 + threadIdx.x;
    if (i < n) out[i] = f2b(in[i]);
}

// ---------------------------------------------------------------------------
// x [b][c][hw] fp32  ->  Xt [b][hw][384] bf16 (transpose+convert, 64x64 tiles)
// ---------------------------------------------------------------------------
__global__ __launch_bounds__(256) void k_cvtx(const float* __restrict__ X, short* __restrict__ Xt) {
    int hw0 = blockIdx.x * 64, c0 = blockIdx.y * 64, b = blockIdx.z;
    __shared__ short S[64 * 72];
    int t = threadIdx.x;
    const float* Xb = X + ((size_t)(b * DIM) << 16);
    short* Xtb = Xt + (size_t)b * HW * DIM;
#pragma unroll
    for (int p = 0; p < 2; ++p) {
        int row = p * 32 + (t >> 3), ch = t & 7;
        const float* src = &Xb[((size_t)(c0 + row) << 16) + hw0 + ch * 8];
        float4 a = *(const float4*)src;
        float4 bq = *(const float4*)(src + 4);
        s16x8 v;
        v[0] = f2b(a.x);  v[1] = f2b(a.y);  v[2] = f2b(a.z);  v[3] = f2b(a.w);
        v[4] = f2b(bq.x); v[5] = f2b(bq.y); v[6] = f2b(bq.z); v[7] = f2b(bq.w);
        *(s16x8*)&S[row * 72 + ch * 8] = v;
    }
    __syncthreads();
#pragma unroll
    for (int p = 0; p < 2; ++p) {
        int row = p * 32 + (t >> 3), ch = t & 7;
        s16x8 v;
#pragma unroll
        for (int j = 0; j < 8; ++j) v[j] = S[(ch * 8 + j) * 72 + row];
        *(s16x8*)&Xtb[(size_t)(hw0 + row) * DIM + c0 + ch * 8] = v;
    }
}

// ---------------------------------------------------------------------------
// MFMA bf16 GEMM: C[z][m][n] = sum_k A[m][k] * Bt[z][n][k]
// A: [384][K] bf16. Bt: z-strided [N][K] bf16. C: z-strided [384][N] fp32.
// 128x128 tile, BK=32, 256 thr = 4 waves (2x2 of 64x64), 16x16x32 MFMA.
// ---------------------------------------------------------------------------
__global__ __launch_bounds__(256) void k_gemm_bf16(const short* __restrict__ A,
                                                   const short* __restrict__ Bt,
                                                   float* __restrict__ C,
                                                   int N, int K) {
    __shared__ short As[128 * 32];
    __shared__ short Bs[128 * 32];
    const short* Bz = Bt + (size_t)blockIdx.z * (size_t)N * K;
    float* Cz = C + (size_t)blockIdx.z * (size_t)384 * N;
    int n0 = blockIdx.x * 128, m0 = blockIdx.y * 128;
    int tid = threadIdx.x;
    int lane = tid & 63, w = tid >> 6;
    int wr = w >> 1, wc = w & 1;
    int lm = lane & 15, quad = lane >> 4;

    f32x4 acc[4][4];
#pragma unroll
    for (int i = 0; i < 4; ++i)
#pragma unroll
        for (int j = 0; j < 4; ++j) acc[i][j] = 0.f;

    int srow = tid >> 2, sseg = tid & 3;
    for (int k0 = 0; k0 < K; k0 += 32) {
        gl_lds16(A + (size_t)(m0 + srow) * K + k0 + sseg * 8, As + tid * 8);
        gl_lds16(A + (size_t)(m0 + 64 + srow) * K + k0 + sseg * 8, As + (tid + 256) * 8);
        gl_lds16(Bz + (size_t)(n0 + srow) * K + k0 + sseg * 8, Bs + tid * 8);
        gl_lds16(Bz + (size_t)(n0 + 64 + srow) * K + k0 + sseg * 8, Bs + (tid + 256) * 8);
        __syncthreads();
        bf16x8 af[4], bfr[4];
#pragma unroll
        for (int i = 0; i < 4; ++i)
            af[i] = __builtin_bit_cast(bf16x8, *(const s16x8*)&As[(wr * 64 + i * 16 + lm) * 32 + quad * 8]);
#pragma unroll
        for (int j = 0; j < 4; ++j)
            bfr[j] = __builtin_bit_cast(bf16x8, *(const s16x8*)&Bs[(wc * 64 + j * 16 + lm) * 32 + quad * 8]);
#pragma unroll
        for (int i = 0; i < 4; ++i)
#pragma unroll
            for (int j = 0; j < 4; ++j)
                acc[i][j] = __builtin_amdgcn_mfma_f32_16x16x32_bf16(af[i], bfr[j], acc[i][j], 0, 0, 0);
        __syncthreads();
    }
#pragma unroll
    for (int i = 0; i < 4; ++i) {
        int r0 = m0 + wr * 64 + i * 16 + quad * 4;
#pragma unroll
        for (int j = 0; j < 4; ++j) {
            int cidx = n0 + wc * 64 + j * 16 + lm;
#pragma unroll
            for (int r = 0; r < 4; ++r)
                Cz[(size_t)(r0 + r) * N + cidx] = acc[i][j][r];
        }
    }
}

// ---------------------------------------------------------------------------
// in-place per-patch 8x8 circular correlation; one thread = one full patch,
// taps wave-uniform (one channel per block) -> pure-VALU inner loop.
// ---------------------------------------------------------------------------
__global__ __launch_bounds__(256) void k_circ2(float* __restrict__ T, const float* __restrict__ K) {
    int gid = blockIdx.x;
    int q = gid & 3;
    int plane = gid >> 2;             // b*384 + c
    int c = plane % 384;
    const float* Kc = K + c * 64;
    float kt[64];
#pragma unroll
    for (int i = 0; i < 64; ++i) kt[i] = Kc[i];
    int t = threadIdx.x;
    int ph = q * 8 + (t >> 5), pw = t & 31;
    size_t base = ((size_t)plane << 16) + (size_t)(ph * 8) * 256 + pw * 8;
    float p[64];
#pragma unroll
    for (int u = 0; u < 8; ++u) {
        float4 r0 = *(const float4*)&T[base + u * 256];
        float4 r1 = *(const float4*)&T[base + u * 256 + 4];
        p[u * 8 + 0] = r0.x; p[u * 8 + 1] = r0.y; p[u * 8 + 2] = r0.z; p[u * 8 + 3] = r0.w;
        p[u * 8 + 4] = r1.x; p[u * 8 + 5] = r1.y; p[u * 8 + 6] = r1.z; p[u * 8 + 7] = r1.w;
    }
#pragma unroll
    for (int u = 0; u < 8; ++u) {
        float o[8];
#pragma unroll
        for (int v = 0; v < 8; ++v) {
            float acc = 0.f;
#pragma unroll
            for (int a = 0; a < 8; ++a)
#pragma unroll
                for (int b8 = 0; b8 < 8; ++b8)
                    acc += kt[a * 8 + b8] * p[((u + a) & 7) * 8 + ((v + b8) & 7)];
            o[v] = acc;
        }
        *(float4*)&T[base + u * 256] = make_float4(o[0], o[1], o[2], o[3]);
        *(float4*)&T[base + u * 256 + 4] = make_float4(o[4], o[5], o[6], o[7]);
    }
}

// ---------------------------------------------------------------------------
// depthwise 3x3 + gelu-gate -> G bf16 [b][c<192][hw]
// ---------------------------------------------------------------------------
__global__ __launch_bounds__(256) void k_dwgate(const float* __restrict__ Y,
                                                const float* __restrict__ Wdw,
                                                short* __restrict__ G) {
    int bz = blockIdx.z;
    int b = bz / 192;
    int c = bz % 192;
    int h0 = blockIdx.y * 32, w0 = blockIdx.x * 32;
    __shared__ float s1[34 * 34];
    __shared__ float s2[34 * 34];
    const float* Y1 = Y + ((size_t)(b * 384 + c) << 16);
    const float* Y2 = Y + ((size_t)(b * 384 + c + 192) << 16);
    int tid = threadIdx.x;
    for (int i = tid; i < 34 * 34; i += 256) {
        int r = i / 34, cl = i % 34;
        int gh = h0 + r - 1, gw = w0 + cl - 1;
        bool ok = (gh >= 0 && gh < 256 && gw >= 0 && gw < 256);
        float v1 = 0.f, v2 = 0.f;
        if (ok) {
            size_t off = (size_t)gh * 256 + gw;
            v1 = Y1[off];
            v2 = Y2[off];
        }
        s1[i] = v1;
        s2[i] = v2;
    }
    float wa[9], wb[9];
#pragma unroll
    for (int j = 0; j < 9; ++j) {
        wa[j] = Wdw[c * 9 + j];
        wb[j] = Wdw[(c + 192) * 9 + j];
    }
    __syncthreads();
    short* Gc = G + ((size_t)(b * 192 + c) << 16);
#pragma unroll
    for (int kq = 0; kq < 4; ++kq) {
        int idx = tid + kq * 256;
        int r = idx >> 5, cl = idx & 31;
        float z1 = 0.f, z2 = 0.f;
#pragma unroll
        for (int i = 0; i < 3; ++i)
#pragma unroll
            for (int j = 0; j < 3; ++j) {
                z1 += s1[(r + i) * 34 + cl + j] * wa[i * 3 + j];
                z2 += s2[(r + i) * 34 + cl + j] * wb[i * 3 + j];
            }
        float ge = 0.5f * z1 * (1.f + erff(z1 * 0.70710678118654752f));
        Gc[(size_t)(h0 + r) * 256 + w0 + cl] = f2b(ge * z2);
    }
}

// ---------------------------------------------------------------------------
// G [b][c<192][hw] bf16 -> Gt [b][hw][192] bf16
// ---------------------------------------------------------------------------
__global__ __launch_bounds__(256) void k_transG(const short* __restrict__ G, short* __restrict__ Gt) {
    int hw0 = blockIdx.x * 64, c0 = blockIdx.y * 64, b = blockIdx.z;
    __shared__ short S[64 * 72];
    int t = threadIdx.x;
    const short* Gb = G + ((size_t)(b * 192) << 16);
    short* Gtb = Gt + (size_t)b * HW * 192;
#pragma unroll
    for (int p = 0; p < 2; ++p) {
        int row = p * 32 + (t >> 3), ch = t & 7;
        s16x8 v = *(const s16x8*)&Gb[((size_t)(c0 + row) << 16) + hw0 + ch * 8];
        *(s16x8*)&S[row * 72 + ch * 8] = v;
    }
    __syncthreads();
#pragma unroll
    for (int p = 0; p < 2; ++p) {
        int row = p * 32 + (t >> 3), ch = t & 7;
        s16x8 v;
#pragma unroll
        for (int j = 0; j < 8; ++j) v[j] = S[(ch * 8 + j) * 72 + row];
        *(s16x8*)&Gtb[(size_t)(hw0 + row) * 192 + c0 + ch * 8] = v;
    }
}

// ---------------------------------------------------------------------------
extern "C" void kernel_launch(void* const* d_in, const int* in_sizes, int n_in,
                              void* d_out, int out_size, void* d_ws, size_t ws_size,
                              hipStream_t stream) {
    const float* x     = (const float*)d_in[0];
    const float* ff    = (const float*)d_in[1];
    const float* w_in  = (const float*)d_in[2];
    const float* w_dw  = (const float*)d_in[3];
    const float* w_out = (const float*)d_in[4];
    float* out = (float*)d_out;

    char* ws = (char*)d_ws;
    float* Kbuf = (float*)ws;                                  // 98304 B
    short* wbin = (short*)(ws + 98304);                        // 294912 B
    short* wbout = (short*)(ws + 393216);                      // 147456 B
    short* xbT = (short*)(ws + 540672);                        // 100663296 B
    float* T   = (float*)(ws + 540672 + (size_t)100663296);    // 201326592 B
    // after GEMM1, xbT is dead: reuse its space for G and Gt (bf16, 48 MiB each)
    short* G  = xbT;
    short* Gt = (short*)((char*)xbT + (size_t)50331648);

    k_precompute<<<384, 64, 0, stream>>>(ff, Kbuf);
    k_cvtw<<<(DIM * DIM + 255) / 256, 256, 0, stream>>>(w_in, wbin, DIM * DIM);
    k_cvtw<<<(DIM * 192 + 255) / 256, 256, 0, stream>>>(w_out, wbout, DIM * 192);
    k_cvtx<<<dim3(HW / 64, DIM / 64, BB), 256, 0, stream>>>(x, xbT);

    // GEMM1: T = w_in @ x   (M=384, N=65536/batch, K=384)
    k_gemm_bf16<<<dim3(HW / 128, 3, BB), 256, 0, stream>>>(wbin, xbT, T, HW, DIM);

    // per-patch circular conv (in place)
    k_circ2<<<BB * 384 * 4, 256, 0, stream>>>(T, Kbuf);

    // depthwise 3x3 + gelu-gate
    k_dwgate<<<dim3(8, 8, BB * 192), 256, 0, stream>>>(T, w_dw, G);

    // transpose G -> Gt [hw][192]
    k_transG<<<dim3(HW / 64, 3, BB), 256, 0, stream>>>(G, Gt);

    // GEMM2: out = w_out @ g  (M=384, N=65536/batch, K=192)
    k_gemm_bf16<<<dim3(HW / 128, 3, BB), 256, 0, stream>>>(wbout, Gt, out, HW, 192);
}

// Round 3
// 660.827 us; speedup vs baseline: 2.1268x; 1.0585x over previous
//
#include <hip/hip_runtime.h>
#include <hip/hip_bf16.h>
#include <math.h>

#define BB 2
#define DIM 384
#define HID 384
#define HW 65536

typedef short s16x8 __attribute__((ext_vector_type(8)));
typedef __bf16 bf16x8 __attribute__((ext_vector_type(8)));
typedef float f32x4 __attribute__((ext_vector_type(4)));

__device__ inline short f2b(float f) {
    __hip_bfloat16 h = __float2bfloat16(f);
    return __builtin_bit_cast(short, h);
}
__device__ inline float b2f(short s) {
    return __bfloat162float(__builtin_bit_cast(__hip_bfloat16, s));
}

__device__ inline void gl_lds16(const short* g, short* l) {
    __builtin_amdgcn_global_load_lds(
        (const __attribute__((address_space(1))) unsigned int*)g,
        (__attribute__((address_space(3))) unsigned int*)l, 16, 0, 0);
}

// ---------------------------------------------------------------------------
// A: per-channel 8x8 circular-correlation taps from fft_filter
// ---------------------------------------------------------------------------
__global__ void k_precompute(const float* __restrict__ F, float* __restrict__ K) {
    int c = blockIdx.x;
    int t = threadIdx.x;
    int a = t >> 3, b = t & 7;
    const float ctab[8] = {1.f, 0.70710678118654752f, 0.f, -0.70710678118654752f,
                           -1.f, -0.70710678118654752f, 0.f, 0.70710678118654752f};
    const float* Fc = F + c * 40;
    float acc = 0.f;
#pragma unroll
    for (int up = 0; up < 8; ++up) {
#pragma unroll
        for (int vp = 0; vp < 5; ++vp) {
            float wv = (vp == 0 || vp == 4) ? 1.f : 2.f;
            int k = (a * up + b * vp) & 7;
            acc += wv * Fc[up * 5 + vp] * ctab[k];
        }
    }
    K[c * 64 + t] = acc * (1.f / 64.f);
}

__global__ void k_cvtw(const float* __restrict__ in, short* __restrict__ out, int n) {
    int i = blockIdx.x * 256 + threadIdx.x;
    if (i < n) out[i] = f2b(in[i]);
}

// ---------------------------------------------------------------------------
// x [b][c][hw] fp32  ->  Xt [b][hw][384] bf16
// ---------------------------------------------------------------------------
__global__ __launch_bounds__(256) void k_cvtx(const float* __restrict__ X, short* __restrict__ Xt) {
    int hw0 = blockIdx.x * 64, c0 = blockIdx.y * 64, b = blockIdx.z;
    __shared__ short S[64 * 72];
    int t = threadIdx.x;
    const float* Xb = X + ((size_t)(b * DIM) << 16);
    short* Xtb = Xt + (size_t)b * HW * DIM;
#pragma unroll
    for (int p = 0; p < 2; ++p) {
        int row = p * 32 + (t >> 3), ch = t & 7;
        const float* src = &Xb[((size_t)(c0 + row) << 16) + hw0 + ch * 8];
        float4 a = *(const float4*)src;
        float4 bq = *(const float4*)(src + 4);
        s16x8 v;
        v[0] = f2b(a.x);  v[1] = f2b(a.y);  v[2] = f2b(a.z);  v[3] = f2b(a.w);
        v[4] = f2b(bq.x); v[5] = f2b(bq.y); v[6] = f2b(bq.z); v[7] = f2b(bq.w);
        *(s16x8*)&S[row * 72 + ch * 8] = v;
    }
    __syncthreads();
#pragma unroll
    for (int p = 0; p < 2; ++p) {
        int row = p * 32 + (t >> 3), ch = t & 7;
        s16x8 v;
#pragma unroll
        for (int j = 0; j < 8; ++j) v[j] = S[(ch * 8 + j) * 72 + row];
        *(s16x8*)&Xtb[(size_t)(hw0 + row) * DIM + c0 + ch * 8] = v;
    }
}

// ---------------------------------------------------------------------------
// Fused GEMM1 + per-patch circular conv.
// N-tile = 8 h-rows x 16 w (2 full 8x8 patches). M-tile = 128 channels.
// T output: bf16 [b][384][256][256]
// ---------------------------------------------------------------------------
__global__ __launch_bounds__(256) void k_gemm1_circ(const short* __restrict__ A,
                                                    const short* __restrict__ Bt,
                                                    const float* __restrict__ Kt,
                                                    short* __restrict__ T) {
    __shared__ short As[128 * 32];
    __shared__ short Bs[128 * 32];
    __shared__ short Ep[128 * 136];   // acc tile bf16, stride 136 (16B-aligned rows)
    int tx = blockIdx.x;
    int h0 = (tx >> 4) * 8;
    int w0 = (tx & 15) * 16;
    int m0 = blockIdx.y * 128;
    int b  = blockIdx.z;
    const short* Bz = Bt + (size_t)b * HW * DIM;
    int tid = threadIdx.x;
    int lane = tid & 63, w = tid >> 6;
    int wr = w >> 1, wc = w & 1;
    int lm = lane & 15, quad = lane >> 4;

    f32x4 acc[4][4];
#pragma unroll
    for (int i = 0; i < 4; ++i)
#pragma unroll
        for (int j = 0; j < 4; ++j) acc[i][j] = 0.f;

    int srow = tid >> 2, sseg = tid & 3;
    int p1 = ((h0 + (srow >> 4)) << 8) + w0 + (srow & 15);
    int p2 = ((h0 + ((srow + 64) >> 4)) << 8) + w0 + ((srow + 64) & 15);
    for (int k0 = 0; k0 < DIM; k0 += 32) {
        gl_lds16(A + (size_t)(m0 + srow) * DIM + k0 + sseg * 8, As + tid * 8);
        gl_lds16(A + (size_t)(m0 + 64 + srow) * DIM + k0 + sseg * 8, As + (tid + 256) * 8);
        gl_lds16(Bz + (size_t)p1 * DIM + k0 + sseg * 8, Bs + tid * 8);
        gl_lds16(Bz + (size_t)p2 * DIM + k0 + sseg * 8, Bs + (tid + 256) * 8);
        __syncthreads();
        bf16x8 af[4], bfr[4];
#pragma unroll
        for (int i = 0; i < 4; ++i)
            af[i] = __builtin_bit_cast(bf16x8, *(const s16x8*)&As[(wr * 64 + i * 16 + lm) * 32 + quad * 8]);
#pragma unroll
        for (int j = 0; j < 4; ++j)
            bfr[j] = __builtin_bit_cast(bf16x8, *(const s16x8*)&Bs[(wc * 64 + j * 16 + lm) * 32 + quad * 8]);
#pragma unroll
        for (int i = 0; i < 4; ++i)
#pragma unroll
            for (int j = 0; j < 4; ++j)
                acc[i][j] = __builtin_amdgcn_mfma_f32_16x16x32_bf16(af[i], bfr[j], acc[i][j], 0, 0, 0);
        __syncthreads();
    }
    // dump acc tile (bf16) into Ep[m_local][n_local]
#pragma unroll
    for (int i = 0; i < 4; ++i)
#pragma unroll
        for (int j = 0; j < 4; ++j)
#pragma unroll
            for (int r = 0; r < 4; ++r)
                Ep[(wr * 64 + i * 16 + quad * 4 + r) * 136 + wc * 64 + j * 16 + lm] =
                    f2b(acc[i][j][r]);
    __syncthreads();

    // one thread per (channel_local, patch): 64-tap circular correlation
    int ch_l = tid >> 1;
    int pat = tid & 1;
    int ch = m0 + ch_l;
    const float* Kc = Kt + ch * 64;
    float kt[64];
#pragma unroll
    for (int i = 0; i < 16; ++i) {
        float4 q = *(const float4*)&Kc[i * 4];
        kt[i * 4 + 0] = q.x; kt[i * 4 + 1] = q.y; kt[i * 4 + 2] = q.z; kt[i * 4 + 3] = q.w;
    }
    float p[64];
#pragma unroll
    for (int u = 0; u < 8; ++u) {
        s16x8 rv = *(const s16x8*)&Ep[ch_l * 136 + u * 16 + pat * 8];
#pragma unroll
        for (int j = 0; j < 8; ++j) p[u * 8 + j] = b2f(rv[j]);
    }
    short* Tp = T + (((size_t)(b * HID + ch)) << 16) + (size_t)h0 * 256 + w0 + pat * 8;
#pragma unroll
    for (int u = 0; u < 8; ++u) {
        s16x8 ov;
#pragma unroll
        for (int v = 0; v < 8; ++v) {
            float acc2 = 0.f;
#pragma unroll
            for (int a = 0; a < 8; ++a)
#pragma unroll
                for (int b8 = 0; b8 < 8; ++b8)
                    acc2 += kt[a * 8 + b8] * p[((u + a) & 7) * 8 + ((v + b8) & 7)];
            ov[v] = f2b(acc2);
        }
        *(s16x8*)&Tp[(size_t)u * 256] = ov;
    }
}

// ---------------------------------------------------------------------------
// depthwise 3x3 + gelu-gate on bf16 T -> G bf16 [b][c<192][hw]
// ---------------------------------------------------------------------------
__global__ __launch_bounds__(256) void k_dwgate(const short* __restrict__ Y,
                                                const float* __restrict__ Wdw,
                                                short* __restrict__ G) {
    int bz = blockIdx.z;
    int b = bz / 192;
    int c = bz % 192;
    int h0 = blockIdx.y * 32, w0 = blockIdx.x * 32;
    __shared__ float s1[34 * 34];
    __shared__ float s2[34 * 34];
    const short* Y1 = Y + ((size_t)(b * HID + c) << 16);
    const short* Y2 = Y + ((size_t)(b * HID + c + 192) << 16);
    int tid = threadIdx.x;
    for (int i = tid; i < 34 * 34; i += 256) {
        int r = i / 34, cl = i % 34;
        int gh = h0 + r - 1, gw = w0 + cl - 1;
        bool ok = (gh >= 0 && gh < 256 && gw >= 0 && gw < 256);
        float v1 = 0.f, v2 = 0.f;
        if (ok) {
            size_t off = (size_t)gh * 256 + gw;
            v1 = b2f(Y1[off]);
            v2 = b2f(Y2[off]);
        }
        s1[i] = v1;
        s2[i] = v2;
    }
    float wa[9], wb[9];
#pragma unroll
    for (int j = 0; j < 9; ++j) {
        wa[j] = Wdw[c * 9 + j];
        wb[j] = Wdw[(c + 192) * 9 + j];
    }
    __syncthreads();
    short* Gc = G + ((size_t)(b * 192 + c) << 16);
#pragma unroll
    for (int kq = 0; kq < 4; ++kq) {
        int idx = tid + kq * 256;
        int r = idx >> 5, cl = idx & 31;
        float z1 = 0.f, z2 = 0.f;
#pragma unroll
        for (int i = 0; i < 3; ++i)
#pragma unroll
            for (int j = 0; j < 3; ++j) {
                z1 += s1[(r + i) * 34 + cl + j] * wa[i * 3 + j];
                z2 += s2[(r + i) * 34 + cl + j] * wb[i * 3 + j];
            }
        float ge = 0.5f * z1 * (1.f + erff(z1 * 0.70710678118654752f));
        Gc[(size_t)(h0 + r) * 256 + w0 + cl] = f2b(ge * z2);
    }
}

// ---------------------------------------------------------------------------
// G [b][c<192][hw] bf16 -> Gt [b][hw][192] bf16
// ---------------------------------------------------------------------------
__global__ __launch_bounds__(256) void k_transG(const short* __restrict__ G, short* __restrict__ Gt) {
    int hw0 = blockIdx.x * 64, c0 = blockIdx.y * 64, b = blockIdx.z;
    __shared__ short S[64 * 72];
    int t = threadIdx.x;
    const short* Gb = G + ((size_t)(b * 192) << 16);
    short* Gtb = Gt + (size_t)b * HW * 192;
#pragma unroll
    for (int p = 0; p < 2; ++p) {
        int row = p * 32 + (t >> 3), ch = t & 7;
        s16x8 v = *(const s16x8*)&Gb[((size_t)(c0 + row) << 16) + hw0 + ch * 8];
        *(s16x8*)&S[row * 72 + ch * 8] = v;
    }
    __syncthreads();
#pragma unroll
    for (int p = 0; p < 2; ++p) {
        int row = p * 32 + (t >> 3), ch = t & 7;
        s16x8 v;
#pragma unroll
        for (int j = 0; j < 8; ++j) v[j] = S[(ch * 8 + j) * 72 + row];
        *(s16x8*)&Gtb[(size_t)(hw0 + row) * 192 + c0 + ch * 8] = v;
    }
}

// ---------------------------------------------------------------------------
// MFMA bf16 GEMM (GEMM2): C[z][m][n] = sum_k A[m][k] * Bt[z][n][k], C fp32
// ---------------------------------------------------------------------------
__global__ __launch_bounds__(256) void k_gemm_bf16(const short* __restrict__ A,
                                                   const short* __restrict__ Bt,
                                                   float* __restrict__ C,
                                                   int N, int K) {
    __shared__ short As[128 * 32];
    __shared__ short Bs[128 * 32];
    const short* Bz = Bt + (size_t)blockIdx.z * (size_t)N * K;
    float* Cz = C + (size_t)blockIdx.z * (size_t)384 * N;
    int n0 = blockIdx.x * 128, m0 = blockIdx.y * 128;
    int tid = threadIdx.x;
    int lane = tid & 63, w = tid >> 6;
    int wr = w >> 1, wc = w & 1;
    int lm = lane & 15, quad = lane >> 4;

    f32x4 acc[4][4];
#pragma unroll
    for (int i = 0; i < 4; ++i)
#pragma unroll
        for (int j = 0; j < 4; ++j) acc[i][j] = 0.f;

    int srow = tid >> 2, sseg = tid & 3;
    for (int k0 = 0; k0 < K; k0 += 32) {
        gl_lds16(A + (size_t)(m0 + srow) * K + k0 + sseg * 8, As + tid * 8);
        gl_lds16(A + (size_t)(m0 + 64 + srow) * K + k0 + sseg * 8, As + (tid + 256) * 8);
        gl_lds16(Bz + (size_t)(n0 + srow) * K + k0 + sseg * 8, Bs + tid * 8);
        gl_lds16(Bz + (size_t)(n0 + 64 + srow) * K + k0 + sseg * 8, Bs + (tid + 256) * 8);
        __syncthreads();
        bf16x8 af[4], bfr[4];
#pragma unroll
        for (int i = 0; i < 4; ++i)
            af[i] = __builtin_bit_cast(bf16x8, *(const s16x8*)&As[(wr * 64 + i * 16 + lm) * 32 + quad * 8]);
#pragma unroll
        for (int j = 0; j < 4; ++j)
            bfr[j] = __builtin_bit_cast(bf16x8, *(const s16x8*)&Bs[(wc * 64 + j * 16 + lm) * 32 + quad * 8]);
#pragma unroll
        for (int i = 0; i < 4; ++i)
#pragma unroll
            for (int j = 0; j < 4; ++j)
                acc[i][j] = __builtin_amdgcn_mfma_f32_16x16x32_bf16(af[i], bfr[j], acc[i][j], 0, 0, 0);
        __syncthreads();
    }
#pragma unroll
    for (int i = 0; i < 4; ++i) {
        int r0 = m0 + wr * 64 + i * 16 + quad * 4;
#pragma unroll
        for (int j = 0; j < 4; ++j) {
            int cidx = n0 + wc * 64 + j * 16 + lm;
#pragma unroll
            for (int r = 0; r < 4; ++r)
                Cz[(size_t)(r0 + r) * N + cidx] = acc[i][j][r];
        }
    }
}

// ---------------------------------------------------------------------------
extern "C" void kernel_launch(void* const* d_in, const int* in_sizes, int n_in,
                              void* d_out, int out_size, void* d_ws, size_t ws_size,
                              hipStream_t stream) {
    const float* x     = (const float*)d_in[0];
    const float* ff    = (const float*)d_in[1];
    const float* w_in  = (const float*)d_in[2];
    const float* w_dw  = (const float*)d_in[3];
    const float* w_out = (const float*)d_in[4];
    float* out = (float*)d_out;

    char* ws = (char*)d_ws;
    float* Kbuf = (float*)ws;                                    // 98304 B
    short* wbin = (short*)(ws + 98304);                          // 294912 B
    short* wbout = (short*)(ws + 393216);                        // 147456 B
    short* xbT = (short*)(ws + 540672);                          // 100663296 B (bf16 x^T)
    short* T   = (short*)(ws + 540672 + (size_t)100663296);      // 100663296 B (bf16 T)
    // after GEMM1, xbT is dead: reuse for G and Gt (bf16, 48 MiB each)
    short* G  = xbT;
    short* Gt = (short*)((char*)xbT + (size_t)50331648);

    k_precompute<<<384, 64, 0, stream>>>(ff, Kbuf);
    k_cvtw<<<(DIM * DIM + 255) / 256, 256, 0, stream>>>(w_in, wbin, DIM * DIM);
    k_cvtw<<<(DIM * 192 + 255) / 256, 256, 0, stream>>>(w_out, wbout, DIM * 192);
    k_cvtx<<<dim3(HW / 64, DIM / 64, BB), 256, 0, stream>>>(x, xbT);

    // fused GEMM1 + circular conv -> T bf16
    k_gemm1_circ<<<dim3(512, 3, BB), 256, 0, stream>>>(wbin, xbT, Kbuf, T);

    // depthwise 3x3 + gelu-gate -> G bf16
    k_dwgate<<<dim3(8, 8, BB * 192), 256, 0, stream>>>(T, w_dw, G);

    // transpose G -> Gt [hw][192]
    k_transG<<<dim3(HW / 64, 3, BB), 256, 0, stream>>>(G, Gt);

    // GEMM2: out = w_out @ g  (M=384, N=65536/batch, K=192)
    k_gemm_bf16<<<dim3(HW / 128, 3, BB), 256, 0, stream>>>(wbout, Gt, out, HW, 192);
}